// Round 1
// baseline (9.360 us; speedup 1.0000x reference)
//
#include <hip/hip_runtime.h>

// ELBO: out[b] = -sum_c log(decoded[b, ctx[b,c]]) + sum_e KL_term(b,e)
// B=4096 CTX=20 EMBED=100 VOCAB=50000; all f32 except context (int32).
// Strategy: one 64-lane wave per example. Lanes cover embed dims (coalesced),
// lanes 0..19 do the decoded gather. Butterfly shuffle-reduce, lane 0 stores.

constexpr int B_     = 4096;
constexpr int CTX_   = 20;
constexpr int EMBED_ = 100;
constexpr int VOCAB_ = 50000;

__global__ __launch_bounds__(256) void elbo_kernel(
    const int*   __restrict__ context,       // [B, CTX]
    const float* __restrict__ mu_lambda,     // [B, EMBED]
    const float* __restrict__ sigma_lambda,  // [B, EMBED]
    const float* __restrict__ mu_x,          // [B, EMBED]
    const float* __restrict__ sigma_x,       // [B, EMBED]
    const float* __restrict__ decoded,       // [B, VOCAB]
    float*       __restrict__ out)           // [B]
{
    const int wave = (int)((blockIdx.x * blockDim.x + threadIdx.x) >> 6);
    const int lane = (int)(threadIdx.x & 63);
    if (wave >= B_) return;

    const float* mul = mu_lambda    + (size_t)wave * EMBED_;
    const float* sl  = sigma_lambda + (size_t)wave * EMBED_;
    const float* mux = mu_x         + (size_t)wave * EMBED_;
    const float* sx  = sigma_x      + (size_t)wave * EMBED_;

    float acc = 0.0f;

    // KL terms: e = lane (all 64 lanes), e = lane + 64 (lanes 0..35)
    {
        int e = lane;
        float s_l = sl[e], s_x = sx[e];
        float dmu = mul[e] - mux[e];
        acc += __logf(s_x) - __logf(s_l)
             + (s_l * s_l + dmu * dmu) / (2.0f * s_x * s_x) - 0.5f;
    }
    if (lane + 64 < EMBED_) {
        int e = lane + 64;
        float s_l = sl[e], s_x = sx[e];
        float dmu = mul[e] - mux[e];
        acc += __logf(s_x) - __logf(s_l)
             + (s_l * s_l + dmu * dmu) / (2.0f * s_x * s_x) - 0.5f;
    }

    // log-likelihood gather: lanes 0..19
    if (lane < CTX_) {
        int idx = context[(size_t)wave * CTX_ + lane];
        float g = decoded[(size_t)wave * VOCAB_ + idx];
        acc -= __logf(g);
    }

    // 64-lane butterfly reduce
    #pragma unroll
    for (int off = 32; off > 0; off >>= 1)
        acc += __shfl_xor(acc, off, 64);

    if (lane == 0) out[wave] = acc;
}

extern "C" void kernel_launch(void* const* d_in, const int* in_sizes, int n_in,
                              void* d_out, int out_size, void* d_ws, size_t ws_size,
                              hipStream_t stream) {
    const int*   context      = (const int*)  d_in[0];
    const float* mu_lambda    = (const float*)d_in[1];
    const float* sigma_lambda = (const float*)d_in[2];
    const float* mu_x         = (const float*)d_in[3];
    const float* sigma_x      = (const float*)d_in[4];
    const float* decoded      = (const float*)d_in[5];
    float* out = (float*)d_out;

    // One wave per example: 4096 waves -> 1024 blocks of 256 threads (4 waves).
    const int threads = 256;
    const int blocks  = (B_ * 64) / threads;  // 1024
    elbo_kernel<<<blocks, threads, 0, stream>>>(
        context, mu_lambda, sigma_lambda, mu_x, sigma_x, decoded, out);
}